// Round 6
// baseline (86.588 us; speedup 1.0000x reference)
//
#include <hip/hip_runtime.h>

#define GRIDC 32

// clang ext-vector so __builtin_nontemporal_load works on 16B values
typedef float fv4 __attribute__((ext_vector_type(4)));

// B=128, NP=32, NS=2048 -> 65536 points/batch, 8388608 total.
// 4096 blocks x 256 threads. XCD-aware swizzle: batch b runs only on XCD b&7,
// so each XCD's 4MB L2 holds the ~8 concurrently-active batches' CP slices
// (8 x 393KB = 3.1MB) -> gathers are L2 hits.
// Streaming inputs (point/tsdf) are read ONCE -> nontemporal loads (nt flag)
// so they don't evict CP from L2.
// Each block = ONE primitive = 2048 contiguous points (uniform inUse).
// Each thread: 2 independent groups of 4 points. Partial -> ws[blk] (no atomics).
__global__ __launch_bounds__(256, 8) void cd_main(
    const float* __restrict__ point, const float* __restrict__ CP,
    const float* __restrict__ tsdfOut, const float* __restrict__ tsdfGT,
    const int* __restrict__ inUse, float* __restrict__ partial)
{
    const int P    = blockIdx.x;
    const int xcd  = P & 7;
    const int idx  = P >> 3;                    // 0..511 within this XCD
    const int b    = ((idx >> 5) << 3) | xcd;   // batch: 16 per XCD
    const int prim = idx & 31;                  // primitive (2048 points each)

    const float useF = (inUse[(b << 5) + prim] == 1) ? 1.0f : 0.0f;

    const long long base = (((long long)b << 5) | prim) << 11;  // first point

    const float* cpb = CP + (long long)b * (GRIDC * GRIDC * GRIDC * 3);

    float lsum = 0.0f;

    #pragma unroll
    for (int j = 0; j < 2; ++j) {
        const long long i0 = base + (j << 10) + ((long long)threadIdx.x << 2);

        // 4 points = 12 contiguous floats = 3 aligned float4 nt-loads
        const fv4* pbase = (const fv4*)(point + i0 * 3);
        const fv4 pA = __builtin_nontemporal_load(pbase + 0);
        const fv4 pB = __builtin_nontemporal_load(pbase + 1);
        const fv4 pC = __builtin_nontemporal_load(pbase + 2);
        const fv4 to4 = __builtin_nontemporal_load((const fv4*)(tsdfOut + i0));
        const fv4 tg4 = __builtin_nontemporal_load((const fv4*)(tsdfGT + i0));

        const float px[4] = {pA.x, pA.w, pB.z, pC.y};
        const float py[4] = {pA.y, pB.x, pB.w, pC.z};
        const float pz[4] = {pA.z, pB.y, pC.x, pC.w};

        float cx[4], cy[4], cz[4];
        #pragma unroll
        for (int k = 0; k < 4; ++k) {
            // (p + 0.5) * 32, truncate toward zero (== .astype(int32)), clamp
            int ix = (int)((px[k] + 0.5f) * 32.0f);
            int iy = (int)((py[k] + 0.5f) * 32.0f);
            int iz = (int)((pz[k] + 0.5f) * 32.0f);
            ix = min(max(ix, 0), 31);
            iy = min(max(iy, 0), 31);
            iz = min(max(iz, 0), 31);
            const float* c = cpb + ((ix << 10) + (iy << 5) + iz) * 3;
            cx[k] = c[0]; cy[k] = c[1]; cz[k] = c[2];   // cached: keep CP in L2
        }

        float dsum = 0.0f;
        #pragma unroll
        for (int k = 0; k < 4; ++k) {
            const float dx = px[k] - cx[k];
            const float dy = py[k] - cy[k];
            const float dz = pz[k] - cz[k];
            dsum += sqrtf(dx * dx + dy * dy + dz * dz);
        }
        lsum += dsum * useF;   // not-in-use -> closest = point -> dist 0

        lsum += fabsf(sqrtf(to4.x) - tg4.x);
        lsum += fabsf(sqrtf(to4.y) - tg4.y);
        lsum += fabsf(sqrtf(to4.z) - tg4.z);
        lsum += fabsf(sqrtf(to4.w) - tg4.w);
    }

    // wave64 reduce -> LDS -> one partial-store per block (no atomics)
    #pragma unroll
    for (int off = 32; off > 0; off >>= 1)
        lsum += __shfl_down(lsum, off, 64);

    __shared__ float wsum[4];
    const int lane = threadIdx.x & 63;
    const int wid  = threadIdx.x >> 6;
    if (lane == 0) wsum[wid] = lsum;
    __syncthreads();
    if (threadIdx.x == 0)
        partial[P] = wsum[0] + wsum[1] + wsum[2] + wsum[3];
}

// Reduce 4096 float partials -> mean -> out[0]
__global__ __launch_bounds__(256) void cd_finalize(
    const float* __restrict__ partial, float* __restrict__ out)
{
    double d = 0.0;
    #pragma unroll
    for (int j = 0; j < 16; ++j)
        d += (double)partial[threadIdx.x + (j << 8)];

    #pragma unroll
    for (int off = 32; off > 0; off >>= 1)
        d += __shfl_down(d, off, 64);

    __shared__ double wsum[4];
    const int lane = threadIdx.x & 63;
    const int wid  = threadIdx.x >> 6;
    if (lane == 0) wsum[wid] = d;
    __syncthreads();
    if (threadIdx.x == 0)
        out[0] = (float)((wsum[0] + wsum[1] + wsum[2] + wsum[3]) / 8388608.0);
}

extern "C" void kernel_launch(void* const* d_in, const int* in_sizes, int n_in,
                              void* d_out, int out_size, void* d_ws, size_t ws_size,
                              hipStream_t stream) {
    const float* point   = (const float*)d_in[0];
    const float* CP      = (const float*)d_in[1];
    const float* tsdfOut = (const float*)d_in[2];
    const float* tsdfGT  = (const float*)d_in[3];
    const int*   inUse   = (const int*)d_in[4];
    float* partial = (float*)d_ws;     // 4096 floats, fully rewritten each call
    float* out     = (float*)d_out;

    hipLaunchKernelGGL(cd_main, dim3(4096), dim3(256), 0, stream,
                       point, CP, tsdfOut, tsdfGT, inUse, partial);
    hipLaunchKernelGGL(cd_finalize, dim3(1), dim3(256), 0, stream, partial, out);
}

// Round 8
// 59.669 us; speedup vs baseline: 1.4511x; 1.4511x over previous
//
#include <hip/hip_runtime.h>

#define GRIDC 32

typedef float fv4 __attribute__((ext_vector_type(4)));
typedef int   iv4 __attribute__((ext_vector_type(4)));

#define CPB_BYTES (GRIDC*GRIDC*GRIDC*12)      // 393216 bytes per batch slice
#define MAXBOFF   (CPB_BYTES - 16)            // last safe byte offset for 16B load

// B=128, NP=32, NS=2048 -> 65536 points/batch, 8388608 total.
// 4096 blocks x 256 threads. XCD-aware swizzle: batch b runs only on XCD b&7,
// so each XCD's 4MB L2 holds the ~8 concurrently-active batches' CP slices.
// Gathers: inline-asm buffer_load_dwordx4 with sc0 (L1 bypass): each random
// 12B cell moves ~16B L2->CU instead of filling a 64B L1 line (5.3x less).
// Streaming inputs (point/tsdf) use normal cached float4 loads.
// Each block = ONE primitive = 2048 contiguous points (uniform inUse).
__global__ __launch_bounds__(256, 8) void cd_main(
    const float* __restrict__ point, const float* __restrict__ CP,
    const float* __restrict__ tsdfOut, const float* __restrict__ tsdfGT,
    const int* __restrict__ inUse, float* __restrict__ partial)
{
    const int P    = blockIdx.x;
    const int xcd  = P & 7;
    const int idx  = P >> 3;                    // 0..511 within this XCD
    const int b    = ((idx >> 5) << 3) | xcd;   // batch: 16 per XCD
    const int prim = idx & 31;                  // primitive (2048 points each)

    const float useF = (inUse[(b << 5) + prim] == 1) ? 1.0f : 0.0f;

    const long long base = (((long long)b << 5) | prim) << 11;  // first point

    // SRD for this batch's CP slice: base, stride=0, num_records=bytes, raw dword
    const float* cpb = CP + (long long)b * (GRIDC * GRIDC * GRIDC * 3);
    iv4 rsrc;
    rsrc[0] = (int)(unsigned)(uintptr_t)cpb;
    rsrc[1] = (int)((unsigned)(((uintptr_t)cpb) >> 32) & 0xFFFFu);  // stride=0
    rsrc[2] = CPB_BYTES;
    rsrc[3] = 0x00020000;

    float lsum = 0.0f;

    #pragma unroll
    for (int j = 0; j < 2; ++j) {
        const long long i0 = base + (j << 10) + ((long long)threadIdx.x << 2);

        // 4 points = 12 contiguous floats = 3 aligned float4 loads (cached)
        const fv4* pbase = (const fv4*)(point + i0 * 3);
        const fv4 pA = pbase[0], pB = pbase[1], pC = pbase[2];
        const fv4 to4 = *(const fv4*)(tsdfOut + i0);
        const fv4 tg4 = *(const fv4*)(tsdfGT + i0);

        const float px[4] = {pA.x, pA.w, pB.z, pC.y};
        const float py[4] = {pA.y, pB.x, pB.w, pC.z};
        const float pz[4] = {pA.z, pB.y, pC.x, pC.w};

        int  boff[4];
        bool sh[4];
        #pragma unroll
        for (int k = 0; k < 4; ++k) {
            // (p + 0.5) * 32, truncate toward zero (== .astype(int32)), clamp
            int ix = (int)((px[k] + 0.5f) * 32.0f);
            int iy = (int)((py[k] + 0.5f) * 32.0f);
            int iz = (int)((pz[k] + 0.5f) * 32.0f);
            ix = min(max(ix, 0), 31);
            iy = min(max(iy, 0), 31);
            iz = min(max(iz, 0), 31);
            int o = ((ix << 10) + (iy << 5) + iz) * 12;      // byte offset
            sh[k]   = o > MAXBOFF;                           // only cell 32767
            boff[k] = sh[k] ? MAXBOFF : o;
        }

        // issue all 4 gathers (L1-bypass), then one wait + scheduling fence
        fv4 g[4];
        #pragma unroll
        for (int k = 0; k < 4; ++k)
            asm volatile("buffer_load_dwordx4 %0, %1, %2, 0 offen sc0"
                         : "=v"(g[k]) : "v"(boff[k]), "s"(rsrc));
        asm volatile("s_waitcnt vmcnt(0)" ::: "memory");
        __builtin_amdgcn_sched_barrier(0);

        float dsum = 0.0f;
        #pragma unroll
        for (int k = 0; k < 4; ++k) {
            const float cx = sh[k] ? g[k][1] : g[k][0];
            const float cy = sh[k] ? g[k][2] : g[k][1];
            const float cz = sh[k] ? g[k][3] : g[k][2];
            const float dx = px[k] - cx;
            const float dy = py[k] - cy;
            const float dz = pz[k] - cz;
            dsum += sqrtf(dx * dx + dy * dy + dz * dz);
        }
        lsum += dsum * useF;   // not-in-use -> closest = point -> dist 0

        lsum += fabsf(sqrtf(to4.x) - tg4.x);
        lsum += fabsf(sqrtf(to4.y) - tg4.y);
        lsum += fabsf(sqrtf(to4.z) - tg4.z);
        lsum += fabsf(sqrtf(to4.w) - tg4.w);
    }

    // wave64 reduce -> LDS -> one partial-store per block (no atomics)
    #pragma unroll
    for (int off = 32; off > 0; off >>= 1)
        lsum += __shfl_down(lsum, off, 64);

    __shared__ float wsum[4];
    const int lane = threadIdx.x & 63;
    const int wid  = threadIdx.x >> 6;
    if (lane == 0) wsum[wid] = lsum;
    __syncthreads();
    if (threadIdx.x == 0)
        partial[P] = wsum[0] + wsum[1] + wsum[2] + wsum[3];
}

// Reduce 4096 float partials -> mean -> out[0]
__global__ __launch_bounds__(256) void cd_finalize(
    const float* __restrict__ partial, float* __restrict__ out)
{
    double d = 0.0;
    #pragma unroll
    for (int j = 0; j < 16; ++j)
        d += (double)partial[threadIdx.x + (j << 8)];

    #pragma unroll
    for (int off = 32; off > 0; off >>= 1)
        d += __shfl_down(d, off, 64);

    __shared__ double wsum[4];
    const int lane = threadIdx.x & 63;
    const int wid  = threadIdx.x >> 6;
    if (lane == 0) wsum[wid] = d;
    __syncthreads();
    if (threadIdx.x == 0)
        out[0] = (float)((wsum[0] + wsum[1] + wsum[2] + wsum[3]) / 8388608.0);
}

extern "C" void kernel_launch(void* const* d_in, const int* in_sizes, int n_in,
                              void* d_out, int out_size, void* d_ws, size_t ws_size,
                              hipStream_t stream) {
    const float* point   = (const float*)d_in[0];
    const float* CP      = (const float*)d_in[1];
    const float* tsdfOut = (const float*)d_in[2];
    const float* tsdfGT  = (const float*)d_in[3];
    const int*   inUse   = (const int*)d_in[4];
    float* partial = (float*)d_ws;     // 4096 floats, fully rewritten each call
    float* out     = (float*)d_out;

    hipLaunchKernelGGL(cd_main, dim3(4096), dim3(256), 0, stream,
                       point, CP, tsdfOut, tsdfGT, inUse, partial);
    hipLaunchKernelGGL(cd_finalize, dim3(1), dim3(256), 0, stream, partial, out);
}